// Round 6
// baseline (546.093 us; speedup 1.0000x reference)
//
#include <hip/hip_runtime.h>

// R6 = R5 (correct, stage1~110us) + PURE-READ PROBE: 4 passes over W
// (1.07 GB) with zero compute, sum kept alive into an unused ws slot.
// Purpose: direct rocprof visibility (>160us => top-5 by dur_us) of a pure
// read stream's hbm_gbps, to discriminate:
//   H-path  : read-miss path ceiling ~2.4-2.7 TB/s  -> probe ~430us
//   H-struct: stage1's compute loop throttles loads -> probe ~190us @ 5+ TB/s

#define IN_LEN   8192
#define OUT_LEN  8192
#define THREADS  256
#define BLOCKS   1024
#define G        (BLOCKS * THREADS)      // 262144 threads = 128 rows x 2048 col4
#define NCOL4    (OUT_LEN / 4)           // 2048
#define RGROUPS  (G / NCOL4)             // 128 row-groups (splits)
#define ITERS    (IN_LEN / RGROUPS)      // 64 rows per thread

__global__ __launch_bounds__(THREADS, 4)
void matvec_stage1(const float* __restrict__ x,
                   const float* __restrict__ W,
                   float* __restrict__ ws) {
    const int g       = blockIdx.x * THREADS + threadIdx.x;
    const int col4    = g & (NCOL4 - 1);
    const int rowbase = g >> 11;

    __shared__ float xs[ITERS];
    if (threadIdx.x < ITERS) xs[threadIdx.x] = x[rowbase + threadIdx.x * RGROUPS];
    __syncthreads();

    const float4* __restrict__ W4 = (const float4*)W;
    float4 acc = make_float4(0.f, 0.f, 0.f, 0.f);

    size_t p = (size_t)g;
#pragma unroll 8
    for (int s = 0; s < ITERS; ++s) {
        const float4 w  = W4[p];
        const float  xv = xs[s];
        p += G;
        acc.x += xv * w.x;
        acc.y += xv * w.y;
        acc.z += xv * w.z;
        acc.w += xv * w.w;
    }
    ((float4*)ws)[(size_t)rowbase * NCOL4 + col4] = acc;
}

__global__ __launch_bounds__(THREADS)
void matvec_stage2(const float* __restrict__ ws,
                   const float* __restrict__ b,
                   float* __restrict__ out) {
    const int col = blockIdx.x * THREADS + threadIdx.x;
    float s = 0.f;
#pragma unroll 8
    for (int r = 0; r < RGROUPS; ++r)
        s += ws[(size_t)r * OUT_LEN + col];
    out[col] = s + b[col];
}

// ---- PURE-READ PROBE: 4 full passes over W, no compute in the loop. ----
#define PBLOCKS  2048
#define PG       (PBLOCKS * THREADS)     // 524288 threads
#define PPASSES  4
#define PITERS   (IN_LEN * NCOL4 / PG)   // 32 float4 per thread per pass

__global__ __launch_bounds__(THREADS, 8)
void read_probe(const float* __restrict__ W, float* __restrict__ dump) {
    const int g = blockIdx.x * THREADS + threadIdx.x;
    const float4* __restrict__ W4 = (const float4*)W;

    float s0 = 0.f, s1 = 0.f, s2 = 0.f, s3 = 0.f;
    for (int pass = 0; pass < PPASSES; ++pass) {
        size_t p = (size_t)g;
#pragma unroll 8
        for (int i = 0; i < PITERS; ++i) {
            const float4 w = W4[p];
            p += PG;
            s0 += w.x; s1 += w.y; s2 += w.z; s3 += w.w;
        }
    }
    dump[g] = s0 + s1 + s2 + s3;   // keep loads alive; slot unused by stage2
}

extern "C" void kernel_launch(void* const* d_in, const int* in_sizes, int n_in,
                              void* d_out, int out_size, void* d_ws, size_t ws_size,
                              hipStream_t stream) {
    const float* x = (const float*)d_in[0];   // (1, 8192)
    const float* W = (const float*)d_in[1];   // (8192, 8192) row-major
    const float* b = (const float*)d_in[2];   // (8192,)
    float* out = (float*)d_out;               // (1, 8192)
    float* ws  = (float*)d_ws;                // 1 GB scratch (harness poisons 1 GB)

    matvec_stage1<<<dim3(BLOCKS), dim3(THREADS), 0, stream>>>(x, W, ws);
    matvec_stage2<<<dim3(OUT_LEN / THREADS), dim3(THREADS), 0, stream>>>(ws, b, out);

    // probe LAST so it cannot warm caches for stage1
    float* dump = ws + (16 * 1024 * 1024 / 4);   // 16 MB offset, 2 MB region
    read_probe<<<dim3(PBLOCKS), dim3(THREADS), 0, stream>>>(W, dump);
}